// Round 1
// baseline (292.344 us; speedup 1.0000x reference)
//
#include <hip/hip_runtime.h>
#include <hip/hip_bf16.h>

#define NN   30000
#define EE   960000
#define IND  2048
#define NEMB 64
#define NH1  32
#define NH2  16
#define NET  64
#define NB   16

typedef __bf16 bf8 __attribute__((ext_vector_type(8)));
typedef __bf16 bf4 __attribute__((ext_vector_type(4)));
typedef float  f4  __attribute__((ext_vector_type(4)));

__device__ __forceinline__ bf8 bf8_zero() {
    bf8 z;
#pragma unroll
    for (int i = 0; i < 8; i++) z[i] = (__bf16)0.0f;
    return z;
}

// ---------------- weight prep ----------------

// embed [2048][64] f32 -> embT [64][2048] bf16 (n-major, k-contiguous)
__global__ __launch_bounds__(256) void k_embT(const float* __restrict__ embed,
                                              __bf16* __restrict__ embT) {
    int idx = blockIdx.x * 256 + threadIdx.x;   // idx = n*2048 + k
    int n = idx >> 11, k = idx & 2047;
    embT[idx] = (__bf16)embed[k * NEMB + n];
}

// W1[r] = sum_b att1[r,b]*basis1[b]  -> W1T [64][32][64] bf16 (o-major, i-contiguous)
__global__ __launch_bounds__(256) void k_w1t(const float* __restrict__ basis1,
                                             const float* __restrict__ att1,
                                             __bf16* __restrict__ W1T) {
    int r = blockIdx.x;
    __shared__ float a[NB];
    if (threadIdx.x < NB) a[threadIdx.x] = att1[r * NB + threadIdx.x];
    __syncthreads();
    for (int idx = threadIdx.x; idx < NH1 * NEMB; idx += 256) {
        int o = idx >> 6, i = idx & 63;
        float acc = 0.f;
#pragma unroll
        for (int b = 0; b < NB; b++) acc += a[b] * basis1[(b * NEMB + i) * NH1 + o];
        W1T[r * (NH1 * NEMB) + idx] = (__bf16)acc;
    }
}

// W2T [64][16][32] bf16
__global__ __launch_bounds__(256) void k_w2t(const float* __restrict__ basis2,
                                             const float* __restrict__ att2,
                                             __bf16* __restrict__ W2T) {
    int r = blockIdx.x;
    __shared__ float a[NB];
    if (threadIdx.x < NB) a[threadIdx.x] = att2[r * NB + threadIdx.x];
    __syncthreads();
    for (int idx = threadIdx.x; idx < NH2 * NH1; idx += 256) {
        int o = idx >> 5, i = idx & 31;
        float acc = 0.f;
#pragma unroll
        for (int b = 0; b < NB; b++) acc += a[b] * basis2[(b * NH1 + i) * NH2 + o];
        W2T[r * (NH2 * NH1) + idx] = (__bf16)acc;
    }
}

// ---------------- embed GEMM: h0 = (x @ embed)/x_norm -> bf16 ----------------
// block = 256 (4 waves), each wave: 16 rows x 64 cols, K=2048
__global__ __launch_bounds__(256) void k_embed(const float* __restrict__ x,
                                               const float* __restrict__ xnorm,
                                               const __bf16* __restrict__ embT,
                                               __bf16* __restrict__ h0b) {
    int lane = threadIdx.x & 63;
    int wave = threadIdx.x >> 6;
    int rowbase = blockIdx.x * 64 + wave * 16;
    int l15 = lane & 15, kg = lane >> 4;
    int arow = rowbase + l15;
    int arow_c = arow < NN ? arow : NN - 1;   // clamp; garbage rows never stored
    const float*  xp = x + (size_t)arow_c * IND + kg * 8;
    const __bf16* bp = embT + (size_t)l15 * IND + kg * 8;
    f4 acc0 = (f4)0.0f, acc1 = (f4)0.0f, acc2 = (f4)0.0f, acc3 = (f4)0.0f;
#pragma unroll 2
    for (int k0 = 0; k0 < IND; k0 += 32) {
        float4 lo = *(const float4*)(xp + k0);
        float4 hi = *(const float4*)(xp + k0 + 4);
        bf8 av;
        av[0] = (__bf16)lo.x; av[1] = (__bf16)lo.y; av[2] = (__bf16)lo.z; av[3] = (__bf16)lo.w;
        av[4] = (__bf16)hi.x; av[5] = (__bf16)hi.y; av[6] = (__bf16)hi.z; av[7] = (__bf16)hi.w;
        bf8 b0 = *(const bf8*)(bp + k0);
        bf8 b1 = *(const bf8*)(bp + 16 * IND + k0);
        bf8 b2 = *(const bf8*)(bp + 32 * IND + k0);
        bf8 b3 = *(const bf8*)(bp + 48 * IND + k0);
        acc0 = __builtin_amdgcn_mfma_f32_16x16x32_bf16(av, b0, acc0, 0, 0, 0);
        acc1 = __builtin_amdgcn_mfma_f32_16x16x32_bf16(av, b1, acc1, 0, 0, 0);
        acc2 = __builtin_amdgcn_mfma_f32_16x16x32_bf16(av, b2, acc2, 0, 0, 0);
        acc3 = __builtin_amdgcn_mfma_f32_16x16x32_bf16(av, b3, acc3, 0, 0, 0);
    }
#pragma unroll
    for (int j = 0; j < 4; j++) {
        int r = rowbase + kg * 4 + j;        // C row = (lane>>4)*4 + reg
        if (r < NN) {
            float inv = 1.0f / xnorm[r];
            __bf16* hp = h0b + (size_t)r * NEMB + l15;   // C col = lane&15 (+16*ntile)
            hp[0]  = (__bf16)(acc0[j] * inv);
            hp[16] = (__bf16)(acc1[j] * inv);
            hp[32] = (__bf16)(acc2[j] * inv);
            hp[48] = (__bf16)(acc3[j] * inv);
        }
    }
}

// ---------------- layer inits: out = bias + h @ root ----------------
__global__ __launch_bounds__(256) void k_init1(const __bf16* __restrict__ h0b,
                                               const float* __restrict__ root1,
                                               const float* __restrict__ bias1,
                                               float* __restrict__ out1) {
    int lane = threadIdx.x & 63, wave = threadIdx.x >> 6;
    int row = blockIdx.x * 8 + wave * 2 + (lane >> 5);
    int col = lane & 31;
    if (row >= NN) return;
    const __bf16* h = h0b + (size_t)row * NEMB;
    float acc = bias1[col];
#pragma unroll 8
    for (int k = 0; k < NEMB; k++) acc += (float)h[k] * root1[k * NH1 + col];
    out1[(size_t)row * NH1 + col] = acc;
}

__global__ __launch_bounds__(256) void k_init2(const __bf16* __restrict__ h1b,
                                               const float* __restrict__ root2,
                                               const float* __restrict__ bias2,
                                               float* __restrict__ out2) {
    int lane = threadIdx.x & 63, wave = threadIdx.x >> 6;
    int row = blockIdx.x * 16 + wave * 4 + (lane >> 4);
    int col = lane & 15;
    if (row >= NN) return;
    const __bf16* h = h1b + (size_t)row * NH1;
    float acc = bias2[col];
#pragma unroll 8
    for (int k = 0; k < NH1; k++) acc += (float)h[k] * root2[k * NH2 + col];
    out2[(size_t)row * NH2 + col] = acc;
}

// ---------------- edge kernels: per-16-edge MFMA batch + atomic scatter ----------------
// layer 1: K=64 (2 steps), N=32 (2 tiles)
__global__ __launch_bounds__(256) void k_edge1(const int* __restrict__ ei,
                                               const int* __restrict__ et,
                                               const __bf16* __restrict__ h0b,
                                               const __bf16* __restrict__ W1T,
                                               float* __restrict__ out1) {
    int wid = blockIdx.x * 4 + (threadIdx.x >> 6);   // 60000 waves exactly
    int lane = threadIdx.x & 63;
    int l15 = lane & 15, kg = lane >> 4;
    int er = wid * 16 + l15;
    int my_et  = et[er];
    int my_src = ei[er];
    int my_dst = ei[EE + er];
    const __bf16* hp = h0b + (size_t)my_src * NEMB + kg * 8;
    bf8 a0 = *(const bf8*)hp;
    bf8 a1 = *(const bf8*)(hp + 32);
    bf8 zero = bf8_zero();
    f4 c0 = (f4)0.0f, c1 = (f4)0.0f;
    int pos = 0;
    while (pos < 16) {                         // sub-segments by relation (sorted)
        int r = __shfl(my_et, pos);
        unsigned long long bl = __ballot(my_et == r);
        unsigned m16 = (unsigned)(bl & 0xFFFFull);
        int run = __builtin_ctz(~(m16 >> pos));
        int end = pos + run;
        const __bf16* wb = W1T + (size_t)r * (NH1 * NEMB) + (size_t)l15 * NEMB + kg * 8;
        bf8 b00 = *(const bf8*)(wb);
        bf8 b01 = *(const bf8*)(wb + 32);
        bf8 b10 = *(const bf8*)(wb + 16 * NEMB);
        bf8 b11 = *(const bf8*)(wb + 16 * NEMB + 32);
        bool use = (l15 >= pos) && (l15 < end);
        bf8 ua0 = use ? a0 : zero;
        bf8 ua1 = use ? a1 : zero;
        c0 = __builtin_amdgcn_mfma_f32_16x16x32_bf16(ua0, b00, c0, 0, 0, 0);
        c0 = __builtin_amdgcn_mfma_f32_16x16x32_bf16(ua1, b01, c0, 0, 0, 0);
        c1 = __builtin_amdgcn_mfma_f32_16x16x32_bf16(ua0, b10, c1, 0, 0, 0);
        c1 = __builtin_amdgcn_mfma_f32_16x16x32_bf16(ua1, b11, c1, 0, 0, 0);
        pos = end;
    }
#pragma unroll
    for (int j = 0; j < 4; j++) {
        int eidx = kg * 4 + j;                 // C row = edge index in batch
        int dst = __shfl(my_dst, eidx);
        atomicAdd(out1 + (size_t)dst * NH1 + l15,      c0[j]);
        atomicAdd(out1 + (size_t)dst * NH1 + 16 + l15, c1[j]);
    }
}

// layer 2: K=32 (1 step), N=16 (1 tile)
__global__ __launch_bounds__(256) void k_edge2(const int* __restrict__ ei,
                                               const int* __restrict__ et,
                                               const __bf16* __restrict__ h1b,
                                               const __bf16* __restrict__ W2T,
                                               float* __restrict__ out2) {
    int wid = blockIdx.x * 4 + (threadIdx.x >> 6);
    int lane = threadIdx.x & 63;
    int l15 = lane & 15, kg = lane >> 4;
    int er = wid * 16 + l15;
    int my_et  = et[er];
    int my_src = ei[er];
    int my_dst = ei[EE + er];
    bf8 a = *(const bf8*)(h1b + (size_t)my_src * NH1 + kg * 8);
    bf8 zero = bf8_zero();
    f4 c = (f4)0.0f;
    int pos = 0;
    while (pos < 16) {
        int r = __shfl(my_et, pos);
        unsigned long long bl = __ballot(my_et == r);
        unsigned m16 = (unsigned)(bl & 0xFFFFull);
        int run = __builtin_ctz(~(m16 >> pos));
        int end = pos + run;
        bf8 b = *(const bf8*)(W2T + (size_t)r * (NH2 * NH1) + (size_t)l15 * NH1 + kg * 8);
        bool use = (l15 >= pos) && (l15 < end);
        c = __builtin_amdgcn_mfma_f32_16x16x32_bf16(use ? a : zero, b, c, 0, 0, 0);
        pos = end;
    }
#pragma unroll
    for (int j = 0; j < 4; j++) {
        int eidx = kg * 4 + j;
        int dst = __shfl(my_dst, eidx);
        atomicAdd(out2 + (size_t)dst * NH2 + l15, c[j]);
    }
}

// ---------------- relu / recast ----------------
__global__ __launch_bounds__(256) void k_relu1(const float* __restrict__ out1,
                                               __bf16* __restrict__ h1b) {
    int i = blockIdx.x * 256 + threadIdx.x;
    if (i >= NN * NH1 / 4) return;
    float4 v = ((const float4*)out1)[i];
    bf4 o;
    o[0] = (__bf16)fmaxf(v.x, 0.f);
    o[1] = (__bf16)fmaxf(v.y, 0.f);
    o[2] = (__bf16)fmaxf(v.z, 0.f);
    o[3] = (__bf16)fmaxf(v.w, 0.f);
    *(bf4*)(h1b + (size_t)i * 4) = o;
}

__global__ __launch_bounds__(256) void k_relu2(float* __restrict__ o) {
    int i = blockIdx.x * 256 + threadIdx.x;
    if (i >= NN * NH2 / 4) return;
    float4 v = ((float4*)o)[i];
    v.x = fmaxf(v.x, 0.f); v.y = fmaxf(v.y, 0.f);
    v.z = fmaxf(v.z, 0.f); v.w = fmaxf(v.w, 0.f);
    ((float4*)o)[i] = v;
}

// ---------------- launch ----------------
extern "C" void kernel_launch(void* const* d_in, const int* in_sizes, int n_in,
                              void* d_out, int out_size, void* d_ws, size_t ws_size,
                              hipStream_t stream) {
    const float* x      = (const float*)d_in[0];
    const int*   ei     = (const int*)d_in[1];
    const int*   et     = (const int*)d_in[2];
    const float* xnorm  = (const float*)d_in[4];
    const float* embed  = (const float*)d_in[5];
    const float* basis1 = (const float*)d_in[6];
    const float* att1   = (const float*)d_in[7];
    const float* root1  = (const float*)d_in[8];
    const float* bias1  = (const float*)d_in[9];
    const float* basis2 = (const float*)d_in[10];
    const float* att2   = (const float*)d_in[11];
    const float* root2  = (const float*)d_in[12];
    const float* bias2  = (const float*)d_in[13];
    float* out = (float*)d_out;

    char* ws = (char*)d_ws;
    __bf16* embT = (__bf16*)(ws + 0);          // 262144 B
    __bf16* W1T  = (__bf16*)(ws + 262144);     // 262144 B
    __bf16* W2T  = (__bf16*)(ws + 524288);     // 65536 B
    __bf16* h0b  = (__bf16*)(ws + 589824);     // 3,840,000 B
    float*  out1 = (float*) (ws + 4429824);    // 3,840,000 B
    __bf16* h1b  = (__bf16*)(ws + 8269824);    // 1,920,000 B

    k_embT <<<512,  256, 0, stream>>>(embed, embT);
    k_w1t  <<<64,   256, 0, stream>>>(basis1, att1, W1T);
    k_w2t  <<<64,   256, 0, stream>>>(basis2, att2, W2T);
    k_embed<<<469,  256, 0, stream>>>(x, xnorm, embT, h0b);
    k_init1<<<3750, 256, 0, stream>>>(h0b, root1, bias1, out1);
    k_edge1<<<15000,256, 0, stream>>>(ei, et, h0b, W1T, out1);
    k_relu1<<<938,  256, 0, stream>>>(out1, h1b);
    k_init2<<<1875, 256, 0, stream>>>(h1b, root2, bias2, out);
    k_edge2<<<15000,256, 0, stream>>>(ei, et, h1b, W2T, out);
    k_relu2<<<469,  256, 0, stream>>>(out);
}